// Round 1
// baseline (2577.878 us; speedup 1.0000x reference)
//
#include <hip/hip_runtime.h>
#include <math.h>

#define B_TOTAL 262144
#define L_STEPS 20

// Fully fused SDENet forward: one thread per batch row.
// State out[50] lives in VGPRs across all 20 SDE steps; weights are read with
// wave-uniform indices so the backend emits s_load + v_fmac(sgpr) — no LDS.
__global__ __launch_bounds__(256, 2)
void sdenet_fused(const float* __restrict__ x,
                  const float* __restrict__ Wd,     const float* __restrict__ bd,
                  const float* __restrict__ Wdrift, const float* __restrict__ bdrift,
                  const float* __restrict__ W1,     const float* __restrict__ b1,
                  const float* __restrict__ W2,     const float* __restrict__ b2,
                  const float* __restrict__ Wfc,    const float* __restrict__ bfc,
                  const float* __restrict__ noise,
                  float* __restrict__ out_mean,
                  float* __restrict__ out_sigma)
{
    const int b = blockIdx.x * blockDim.x + threadIdx.x;
    if (b >= B_TOTAL) return;

    // ---------------- stage 1: out = x @ Wd.T + bd  (50 out, 90 in) ----------
    float out[50];
    #pragma unroll
    for (int i = 0; i < 50; ++i) out[i] = bd[i];

    const float* xrow = x + (long)b * 90;   // 360 B stride -> 8 B aligned
    // k in chunks of 18 (5 rolled iterations keeps I$ small); float2 loads.
    for (int kk = 0; kk < 90; kk += 18) {
        float xv[18];
        #pragma unroll
        for (int k = 0; k < 18; k += 2) {
            float2 t = *(const float2*)(xrow + kk + k);
            xv[k] = t.x; xv[k + 1] = t.y;
        }
        #pragma unroll
        for (int i = 0; i < 50; ++i) {
            float acc = 0.f;
            #pragma unroll
            for (int k = 0; k < 18; ++k)
                acc += xv[k] * Wd[i * 90 + kk + k];
            out[i] += acc;
        }
    }

    // ------------- stage 2: diffusion = 0.5*sigmoid(W2 @ relu(W1@out+b1) + b2)
    // h is never materialized: reduce each h_i straight into the scalar.
    float dacc = b2[0];
    for (int i = 0; i < 100; ++i) {          // rolled: 50-FMA body
        float acc = b1[i];
        #pragma unroll
        for (int j = 0; j < 50; ++j)
            acc += W1[i * 50 + j] * out[j];
        dacc += W2[i] * fmaxf(acc, 0.f);
    }
    const float diffusion = 0.5f / (1.f + __expf(-dacc));
    const float dt = 0.2f;                       // 4.0 / 20
    const float c  = diffusion * 0.44721359549995794f;  // diffusion * sqrt(dt)

    // ---------------- stage 3: 20 Euler-Maruyama steps ------------------------
    const float* nbase = noise + (long)b * 50;
    for (int l = 0; l < L_STEPS; ++l) {
        const float* nrow = nbase + (long)l * ((long)B_TOTAL * 50);
        // prefetch this step's noise first; HBM latency hides under the matvec
        float nv[50];
        #pragma unroll
        for (int j = 0; j < 50; j += 2) {    // rows only 8B-aligned (200 B)
            float2 t = *(const float2*)(nrow + j);
            nv[j] = t.x; nv[j + 1] = t.y;
        }
        float drift[50];
        #pragma unroll
        for (int i = 0; i < 50; ++i) {
            float acc = bdrift[i];
            #pragma unroll
            for (int j = 0; j < 50; ++j)
                acc += Wdrift[i * 50 + j] * out[j];
            drift[i] = fmaxf(acc, 0.f);
        }
        #pragma unroll
        for (int i = 0; i < 50; ++i)
            out[i] = out[i] + drift[i] * dt + c * nv[i];
    }

    // ---------------- stage 4: head -------------------------------------------
    float m  = bfc[0];
    float s2 = bfc[1];
    #pragma unroll
    for (int j = 0; j < 50; ++j) {
        const float r = fmaxf(out[j], 0.f);
        m  += Wfc[j]      * r;
        s2 += Wfc[50 + j] * r;
    }
    out_mean[b] = m;
    // softplus, overflow-safe
    const float sp = (s2 > 20.f) ? s2 : log1pf(__expf(s2));
    out_sigma[b] = sp + 0.001f;
}

extern "C" void kernel_launch(void* const* d_in, const int* in_sizes, int n_in,
                              void* d_out, int out_size, void* d_ws, size_t ws_size,
                              hipStream_t stream) {
    const float* x      = (const float*)d_in[0];
    const float* Wd     = (const float*)d_in[1];
    const float* bd     = (const float*)d_in[2];
    const float* Wdrift = (const float*)d_in[3];
    const float* bdrift = (const float*)d_in[4];
    const float* W1     = (const float*)d_in[5];
    const float* b1     = (const float*)d_in[6];
    const float* W2     = (const float*)d_in[7];
    const float* b2     = (const float*)d_in[8];
    const float* Wfc    = (const float*)d_in[9];
    const float* bfc    = (const float*)d_in[10];
    const float* noise  = (const float*)d_in[11];

    float* outp = (float*)d_out;           // [0,B) mean, [B,2B) sigma

    dim3 grid(B_TOTAL / 256), block(256);
    hipLaunchKernelGGL(sdenet_fused, grid, block, 0, stream,
                       x, Wd, bd, Wdrift, bdrift, W1, b1, W2, b2, Wfc, bfc,
                       noise, outp, outp + B_TOTAL);
}